// Round 1
// baseline (6834.924 us; speedup 1.0000x reference)
//
#include <hip/hip_runtime.h>
#include <hip/hip_fp16.h>
#include <cstdint>
#include <cstddef>

// Problem constants (reference freezes given_num=64 at trace time).
#define EMBD 1024
#define HIDD 1024
#define G4   4096
#define VOC  32000
#define SEQL 128
#define GN   64
#define NR   64

// JAX RNG mode: 1 = threefry_partitionable (modern JAX default), 0 = legacy stream.
#define JAX_PARTITIONABLE 1

// ---------------- threefry2x32 (JAX-compatible, 20 rounds) ----------------
__device__ __forceinline__ uint32_t rotl32(uint32_t v, int d) { return (v << d) | (v >> (32 - d)); }

__device__ inline void threefry2x32(uint32_t k0, uint32_t k1, uint32_t x0, uint32_t x1,
                                    uint32_t& o0, uint32_t& o1) {
  uint32_t ks2 = k0 ^ k1 ^ 0x1BD11BDAu;
#define TF_ROUND(r) { x0 += x1; x1 = rotl32(x1, r); x1 ^= x0; }
  x0 += k0;  x1 += k1;
  TF_ROUND(13) TF_ROUND(15) TF_ROUND(26) TF_ROUND(6)
  x0 += k1;  x1 += ks2 + 1u;
  TF_ROUND(17) TF_ROUND(29) TF_ROUND(16) TF_ROUND(24)
  x0 += ks2; x1 += k0 + 2u;
  TF_ROUND(13) TF_ROUND(15) TF_ROUND(26) TF_ROUND(6)
  x0 += k0;  x1 += k1 + 3u;
  TF_ROUND(17) TF_ROUND(29) TF_ROUND(16) TF_ROUND(24)
  x0 += k1;  x1 += ks2 + 4u;
  TF_ROUND(13) TF_ROUND(15) TF_ROUND(26) TF_ROUND(6)
  x0 += ks2; x1 += k0 + 5u;
#undef TF_ROUND
  o0 = x0; o1 = x1;
}

// 32-bit random draw for element idx of a length-VOC array under key (k0,k1).
__device__ inline uint32_t rng_bits(uint32_t k0, uint32_t k1, uint32_t idx) {
#if JAX_PARTITIONABLE
  uint32_t h0, h1; threefry2x32(k0, k1, 0u, idx, h0, h1);
  return h0 ^ h1;
#else
  uint32_t h0, h1;
  if (idx < (VOC / 2)) { threefry2x32(k0, k1, idx, idx + (VOC / 2), h0, h1); return h0; }
  else                 { threefry2x32(k0, k1, idx - (VOC / 2), idx, h0, h1); return h1; }
#endif
}

__device__ inline float gumbel_of(uint32_t k0, uint32_t k1, uint32_t idx) {
  uint32_t bits = rng_bits(k0, k1, idx);
  float u = __uint_as_float((bits >> 9) | 0x3f800000u) - 1.0f;   // [0,1)
  u = fmaxf(u, 1.17549435e-38f);                                  // jax uniform(minval=tiny)
  return -logf(-logf(u));
}

// argmax pack: bigger value wins; on exact tie, smaller index wins (jnp.argmax).
__device__ inline unsigned long long packCand(float v, int idx) {
  uint32_t u = __float_as_uint(v);
  u = (u & 0x80000000u) ? ~u : (u | 0x80000000u);
  return ((unsigned long long)u << 32) | (unsigned long long)(0xFFFFFFFFu - (uint32_t)idx);
}

__device__ inline float sigf(float x) { return 1.0f / (1.0f + expf(-x)); }

__device__ __forceinline__ float h2f(unsigned short u) {
  __half_raw hr; hr.x = u;
  return __half2float(__half(hr));
}

// ---------------- init: keys (split of key(123)), zero state ----------------
__global__ void k_init(uint2* keys, unsigned* counters, float* cbuf, float* h0) {
  int t = threadIdx.x;
#if JAX_PARTITIONABLE
  if (t < NR + 1) {
    uint32_t a, b; threefry2x32(0u, 123u, 0u, (uint32_t)t, a, b);
    keys[t] = make_uint2(a, b);
  }
#else
  __shared__ uint32_t buf[2 * (NR + 1)];
  if (t < NR + 1) {
    uint32_t a, b; threefry2x32(0u, 123u, (uint32_t)t, (uint32_t)(t + NR + 1), a, b);
    buf[t] = a; buf[t + NR + 1] = b;
  }
  __syncthreads();
  if (t < NR + 1) keys[t] = make_uint2(buf[2 * t], buf[2 * t + 1]);
#endif
  for (int i = t; i < 66; i += 256) counters[i] = 0u;
  for (int i = t; i < HIDD; i += 256) { cbuf[i] = 0.0f; h0[i] = 0.0f; }
}

// ---------------- Wtag fp32 -> fp16 conversion (once per launch) ----------------
__global__ __launch_bounds__(256) void k_cvt_f16(const float* __restrict__ src,
                                                 unsigned short* __restrict__ dst, int n) {
  int stride = gridDim.x * blockDim.x * 8;
  for (int i = (blockIdx.x * blockDim.x + threadIdx.x) * 8; i < n; i += stride) {
    float4 a = *(const float4*)(src + i);
    float4 b = *(const float4*)(src + i + 4);
    union { unsigned short u[8]; uint4 v; } p;
    __half t;
    t = __float2half(a.x); p.u[0] = __half_raw(t).x;
    t = __float2half(a.y); p.u[1] = __half_raw(t).x;
    t = __float2half(a.z); p.u[2] = __half_raw(t).x;
    t = __float2half(a.w); p.u[3] = __half_raw(t).x;
    t = __float2half(b.x); p.u[4] = __half_raw(t).x;
    t = __float2half(b.y); p.u[5] = __half_raw(t).x;
    t = __float2half(b.z); p.u[6] = __half_raw(t).x;
    t = __float2half(b.w); p.u[7] = __half_raw(t).x;
    *(uint4*)(dst + i) = p.v;
  }
}

// ---------------- gather prefix embeddings ----------------
__global__ void k_gather(const float* __restrict__ emb, const int* __restrict__ sent,
                         float* __restrict__ X) {
  int m = blockIdx.x;
  int row = sent[m];
  const float4* s = (const float4*)(emb + (size_t)row * EMBD);
  float4* d = (float4*)(X + (size_t)m * EMBD);
  d[threadIdx.x] = s[threadIdx.x];  // 256 float4 = 1024 floats
}

// ---------------- GEMM: C[64][N] = A[64][1024] @ B[N][1024]^T (+bias), fp32 B ----------------
__global__ __launch_bounds__(256) void k_gemm64(const float* __restrict__ A,
                                                const float* __restrict__ B,
                                                const float* __restrict__ bias,
                                                float* __restrict__ C, int ldc) {
  __shared__ float As[64][33];
  __shared__ float Bs[64][33];
  int n0 = blockIdx.x * 64;
  int tn = threadIdx.x & 15, tm = threadIdx.x >> 4;
  float acc[4][4] = {{0.f}};
  for (int k0 = 0; k0 < 1024; k0 += 32) {
    for (int f = threadIdx.x; f < 512; f += 256) {
      int r = f >> 3, c4 = (f & 7) << 2;
      float4 v = *(const float4*)(A + (size_t)r * 1024 + k0 + c4);
      As[r][c4 + 0] = v.x; As[r][c4 + 1] = v.y; As[r][c4 + 2] = v.z; As[r][c4 + 3] = v.w;
      float4 u = *(const float4*)(B + (size_t)(n0 + r) * 1024 + k0 + c4);
      Bs[r][c4 + 0] = u.x; Bs[r][c4 + 1] = u.y; Bs[r][c4 + 2] = u.z; Bs[r][c4 + 3] = u.w;
    }
    __syncthreads();
#pragma unroll
    for (int kk = 0; kk < 32; ++kk) {
      float a0 = As[tm * 4 + 0][kk], a1 = As[tm * 4 + 1][kk];
      float a2 = As[tm * 4 + 2][kk], a3 = As[tm * 4 + 3][kk];
      float b0 = Bs[tn * 4 + 0][kk], b1 = Bs[tn * 4 + 1][kk];
      float b2 = Bs[tn * 4 + 2][kk], b3 = Bs[tn * 4 + 3][kk];
      acc[0][0] += a0 * b0; acc[0][1] += a0 * b1; acc[0][2] += a0 * b2; acc[0][3] += a0 * b3;
      acc[1][0] += a1 * b0; acc[1][1] += a1 * b1; acc[1][2] += a1 * b2; acc[1][3] += a1 * b3;
      acc[2][0] += a2 * b0; acc[2][1] += a2 * b1; acc[2][2] += a2 * b2; acc[2][3] += a2 * b3;
      acc[3][0] += a3 * b0; acc[3][1] += a3 * b1; acc[3][2] += a3 * b2; acc[3][3] += a3 * b3;
    }
    __syncthreads();
  }
#pragma unroll
  for (int i = 0; i < 4; ++i)
#pragma unroll
    for (int j = 0; j < 4; ++j) {
      int m = tm * 4 + i, n = n0 + tn * 4 + j;
      float r = acc[i][j] + (bias ? bias[n] : 0.0f);
      C[(size_t)m * ldc + n] = r;
    }
}

// ---------------- GEMM variant: B in fp16 (for W_tag) ----------------
__global__ __launch_bounds__(256) void k_gemm64_f16b(const float* __restrict__ A,
                                                     const unsigned short* __restrict__ B16,
                                                     const float* __restrict__ bias,
                                                     float* __restrict__ C, int ldc) {
  __shared__ float As[64][33];
  __shared__ float Bs[64][33];
  int n0 = blockIdx.x * 64;
  int tn = threadIdx.x & 15, tm = threadIdx.x >> 4;
  float acc[4][4] = {{0.f}};
  for (int k0 = 0; k0 < 1024; k0 += 32) {
    for (int f = threadIdx.x; f < 512; f += 256) {
      int r = f >> 3, c4 = (f & 7) << 2;
      float4 v = *(const float4*)(A + (size_t)r * 1024 + k0 + c4);
      As[r][c4 + 0] = v.x; As[r][c4 + 1] = v.y; As[r][c4 + 2] = v.z; As[r][c4 + 3] = v.w;
    }
    {
      int f = threadIdx.x;
      int r = f >> 2, c8 = (f & 3) << 3;
      union { uint4 v; unsigned short u[8]; } p;
      p.v = *(const uint4*)(B16 + (size_t)(n0 + r) * 1024 + k0 + c8);
#pragma unroll
      for (int j = 0; j < 8; ++j) Bs[r][c8 + j] = h2f(p.u[j]);
    }
    __syncthreads();
#pragma unroll
    for (int kk = 0; kk < 32; ++kk) {
      float a0 = As[tm * 4 + 0][kk], a1 = As[tm * 4 + 1][kk];
      float a2 = As[tm * 4 + 2][kk], a3 = As[tm * 4 + 3][kk];
      float b0 = Bs[tn * 4 + 0][kk], b1 = Bs[tn * 4 + 1][kk];
      float b2 = Bs[tn * 4 + 2][kk], b3 = Bs[tn * 4 + 3][kk];
      acc[0][0] += a0 * b0; acc[0][1] += a0 * b1; acc[0][2] += a0 * b2; acc[0][3] += a0 * b3;
      acc[1][0] += a1 * b0; acc[1][1] += a1 * b1; acc[1][2] += a1 * b2; acc[1][3] += a1 * b3;
      acc[2][0] += a2 * b0; acc[2][1] += a2 * b1; acc[2][2] += a2 * b2; acc[2][3] += a2 * b3;
      acc[3][0] += a3 * b0; acc[3][1] += a3 * b1; acc[3][2] += a3 * b2; acc[3][3] += a3 * b3;
    }
    __syncthreads();
  }
#pragma unroll
  for (int i = 0; i < 4; ++i)
#pragma unroll
    for (int j = 0; j < 4; ++j) {
      int m = tm * 4 + i, n = n0 + tn * 4 + j;
      float r = acc[i][j] + (bias ? bias[n] : 0.0f);
      C[(size_t)m * ldc + n] = r;
    }
}

// ---------------- prefix LSTM step (x-part precomputed in gx) ----------------
__global__ __launch_bounds__(256) void k_lstm_pre(const float* __restrict__ Whh,
                                                  const float* __restrict__ bih,
                                                  const float* __restrict__ bhh,
                                                  const float* __restrict__ gx, int t,
                                                  const float* __restrict__ hprev,
                                                  float* __restrict__ cbuf,
                                                  float* __restrict__ hout) {
  __shared__ float gs[4];
  int wave = threadIdx.x >> 6, lane = threadIdx.x & 63;
  int j = blockIdx.x;
  int r = j + (wave << 10);
  const float4* h4 = (const float4*)hprev;
  const float4* w4 = (const float4*)(Whh + (size_t)r * 1024);
  float a = 0.0f;
#pragma unroll
  for (int q = 0; q < 4; ++q) {
    float4 w = w4[lane + (q << 6)];
    float4 h = h4[lane + (q << 6)];
    a += w.x * h.x + w.y * h.y + w.z * h.z + w.w * h.w;
  }
#pragma unroll
  for (int off = 32; off; off >>= 1) a += __shfl_xor(a, off, 64);
  if (lane == 0) gs[wave] = a + gx[(size_t)t * G4 + r] + bih[r] + bhh[r];
  __syncthreads();
  if (threadIdx.x == 0) {
    float gi = gs[0], gf = gs[1], gg = gs[2], go = gs[3];
    float cn = sigf(gf) * cbuf[j] + sigf(gi) * tanhf(gg);
    cbuf[j] = cn;
    hout[j] = sigf(go) * tanhf(cn);
  }
}

// ---------------- rollout LSTM step (x = emb[tokens[t]]) ----------------
__global__ __launch_bounds__(256) void k_lstm_roll(const float* __restrict__ Wih,
                                                   const float* __restrict__ Whh,
                                                   const float* __restrict__ bih,
                                                   const float* __restrict__ bhh,
                                                   const float* __restrict__ emb,
                                                   const int* __restrict__ tok, int t,
                                                   const float* __restrict__ hprev,
                                                   float* __restrict__ cbuf,
                                                   float* __restrict__ hout) {
  __shared__ float gs[4];
  int wave = threadIdx.x >> 6, lane = threadIdx.x & 63;
  int j = blockIdx.x;
  int r = j + (wave << 10);
  int row = tok[t];
  const float4* x4 = (const float4*)(emb + (size_t)row * EMBD);
  const float4* h4 = (const float4*)hprev;
  const float4* wi = (const float4*)(Wih + (size_t)r * 1024);
  const float4* wh = (const float4*)(Whh + (size_t)r * 1024);
  float a = 0.0f;
#pragma unroll
  for (int q = 0; q < 4; ++q) {
    float4 w = wi[lane + (q << 6)];
    float4 x = x4[lane + (q << 6)];
    a += w.x * x.x + w.y * x.y + w.z * x.z + w.w * x.w;
    w = wh[lane + (q << 6)];
    float4 h = h4[lane + (q << 6)];
    a += w.x * h.x + w.y * h.y + w.z * h.z + w.w * h.w;
  }
#pragma unroll
  for (int off = 32; off; off >>= 1) a += __shfl_xor(a, off, 64);
  if (lane == 0) gs[wave] = a + bih[r] + bhh[r];
  __syncthreads();
  if (threadIdx.x == 0) {
    float gi = gs[0], gf = gs[1], gg = gs[2], go = gs[3];
    float cn = sigf(gf) * cbuf[j] + sigf(gi) * tanhf(gg);
    cbuf[j] = cn;
    hout[j] = sigf(go) * tanhf(cn);
  }
}

// ---------------- logits matvec + gumbel + argmax, fp32 Wtag (fallback) ----------------
__global__ __launch_bounds__(256) void k_logits(const float* __restrict__ Wtag,
                                                const float* __restrict__ btag,
                                                const float* __restrict__ h,
                                                float* __restrict__ outrow,
                                                const uint2* __restrict__ keys, int key_idx,
                                                unsigned long long* __restrict__ partials,
                                                unsigned* __restrict__ counter,
                                                int* __restrict__ token_out) {
  __shared__ float sums[64];
  __shared__ unsigned long long red[256];
  __shared__ int amLast;
  int wave = threadIdx.x >> 6, lane = threadIdx.x & 63;
  int r0 = blockIdx.x * 64;
  const float4* h4 = (const float4*)h;
  float4 hv[4];
#pragma unroll
  for (int q = 0; q < 4; ++q) hv[q] = h4[lane + (q << 6)];
  for (int rr = 0; rr < 16; ++rr) {
    int lr = wave * 16 + rr;
    int r = r0 + lr;
    const float4* w4 = (const float4*)(Wtag + (size_t)r * 1024);
    float a = 0.0f;
#pragma unroll
    for (int q = 0; q < 4; ++q) {
      float4 w = w4[lane + (q << 6)];
      a += w.x * hv[q].x + w.y * hv[q].y + w.z * hv[q].z + w.w * hv[q].w;
    }
#pragma unroll
    for (int off = 32; off; off >>= 1) a += __shfl_xor(a, off, 64);
    if (lane == 0) sums[lr] = a;
  }
  __syncthreads();
  unsigned long long best = 0ull;
  if (threadIdx.x < 64) {
    int r = r0 + threadIdx.x;
    float L = sums[threadIdx.x] + btag[r];
    outrow[r] = L;
    uint2 K = keys[key_idx];
    float y = L + gumbel_of(K.x, K.y, (uint32_t)r);
    best = packCand(y, r);
#pragma unroll
    for (int off = 32; off; off >>= 1) {
      unsigned long long o = __shfl_xor(best, off, 64);
      if (o > best) best = o;
    }
    if (threadIdx.x == 0) partials[blockIdx.x] = best;
  }
  __threadfence();
  __syncthreads();
  if (threadIdx.x == 0) amLast = (atomicAdd(counter, 1u) == gridDim.x - 1) ? 1 : 0;
  __syncthreads();
  if (amLast) {
    __threadfence();
    unsigned long long b = 0ull;
    for (int i = threadIdx.x; i < (int)gridDim.x; i += 256) {
      unsigned long long v = *((volatile unsigned long long*)(partials + i));
      if (v > b) b = v;
    }
    red[threadIdx.x] = b;
    __syncthreads();
    for (int s = 128; s; s >>= 1) {
      if (threadIdx.x < s) {
        if (red[threadIdx.x + s] > red[threadIdx.x]) red[threadIdx.x] = red[threadIdx.x + s];
      }
      __syncthreads();
    }
    if (threadIdx.x == 0)
      token_out[0] = (int)(0xFFFFFFFFu - (uint32_t)(red[0] & 0xFFFFFFFFull));
  }
}

// ---------------- logits matvec + gumbel + argmax, fp16 Wtag (32 rows/block) ----------------
__global__ __launch_bounds__(256) void k_logits_f16(const unsigned short* __restrict__ Wt16,
                                                    const float* __restrict__ btag,
                                                    const float* __restrict__ h,
                                                    float* __restrict__ outrow,
                                                    const uint2* __restrict__ keys, int key_idx,
                                                    unsigned long long* __restrict__ partials,
                                                    unsigned* __restrict__ counter,
                                                    int* __restrict__ token_out) {
  __shared__ float sums[32];
  __shared__ unsigned long long red[256];
  __shared__ int amLast;
  int wave = threadIdx.x >> 6, lane = threadIdx.x & 63;
  int r0 = blockIdx.x * 32;
  const float4* h4 = (const float4*)h;
  // lane covers halfs [q*512 + lane*8, +8) for q=0,1 -> 16 h floats in 4 float4s
  float4 hq[4];
#pragma unroll
  for (int q = 0; q < 2; ++q) {
    hq[2 * q]     = h4[q * 128 + lane * 2];
    hq[2 * q + 1] = h4[q * 128 + lane * 2 + 1];
  }
  for (int rr = 0; rr < 8; ++rr) {
    int lr = wave * 8 + rr;
    int r = r0 + lr;
    const unsigned short* wrow = Wt16 + (size_t)r * 1024;
    float a = 0.0f;
#pragma unroll
    for (int q = 0; q < 2; ++q) {
      union { uint4 v; unsigned short u[8]; } p;
      p.v = *(const uint4*)(wrow + q * 512 + lane * 8);
      float4 hA = hq[2 * q], hB = hq[2 * q + 1];
      a += h2f(p.u[0]) * hA.x; a += h2f(p.u[1]) * hA.y;
      a += h2f(p.u[2]) * hA.z; a += h2f(p.u[3]) * hA.w;
      a += h2f(p.u[4]) * hB.x; a += h2f(p.u[5]) * hB.y;
      a += h2f(p.u[6]) * hB.z; a += h2f(p.u[7]) * hB.w;
    }
#pragma unroll
    for (int off = 32; off; off >>= 1) a += __shfl_xor(a, off, 64);
    if (lane == 0) sums[lr] = a;
  }
  __syncthreads();
  unsigned long long best = 0ull;
  if (threadIdx.x < 64) {
    if (threadIdx.x < 32) {
      int r = r0 + threadIdx.x;
      float L = sums[threadIdx.x] + btag[r];
      outrow[r] = L;
      uint2 K = keys[key_idx];
      float y = L + gumbel_of(K.x, K.y, (uint32_t)r);
      best = packCand(y, r);
    }
#pragma unroll
    for (int off = 32; off; off >>= 1) {
      unsigned long long o = __shfl_xor(best, off, 64);
      if (o > best) best = o;
    }
    if (threadIdx.x == 0) partials[blockIdx.x] = best;
  }
  __threadfence();
  __syncthreads();
  if (threadIdx.x == 0) amLast = (atomicAdd(counter, 1u) == gridDim.x - 1) ? 1 : 0;
  __syncthreads();
  if (amLast) {
    __threadfence();
    unsigned long long b = 0ull;
    for (int i = threadIdx.x; i < (int)gridDim.x; i += 256) {
      unsigned long long v = *((volatile unsigned long long*)(partials + i));
      if (v > b) b = v;
    }
    red[threadIdx.x] = b;
    __syncthreads();
    for (int s = 128; s; s >>= 1) {
      if (threadIdx.x < s) {
        if (red[threadIdx.x + s] > red[threadIdx.x]) red[threadIdx.x] = red[threadIdx.x + s];
      }
      __syncthreads();
    }
    if (threadIdx.x == 0)
      token_out[0] = (int)(0xFFFFFFFFu - (uint32_t)(red[0] & 0xFFFFFFFFull));
  }
}

// ---------------- sample from an existing logits row (initial token) ----------------
__global__ __launch_bounds__(256) void k_sample_row(const float* __restrict__ row,
                                                    const uint2* __restrict__ keys, int key_idx,
                                                    unsigned long long* __restrict__ partials,
                                                    unsigned* __restrict__ counter,
                                                    int* __restrict__ token_out) {
  __shared__ unsigned long long red[256];
  __shared__ int amLast;
  int v = blockIdx.x * 256 + threadIdx.x;
  unsigned long long best = 0ull;
  if (v < VOC) {
    uint2 K = keys[key_idx];
    float y = row[v] + gumbel_of(K.x, K.y, (uint32_t)v);
    best = packCand(y, v);
  }
  red[threadIdx.x] = best;
  __syncthreads();
  for (int s = 128; s; s >>= 1) {
    if (threadIdx.x < s) {
      if (red[threadIdx.x + s] > red[threadIdx.x]) red[threadIdx.x] = red[threadIdx.x + s];
    }
    __syncthreads();
  }
  if (threadIdx.x == 0) partials[blockIdx.x] = red[0];
  __threadfence();
  __syncthreads();
  if (threadIdx.x == 0) amLast = (atomicAdd(counter, 1u) == gridDim.x - 1) ? 1 : 0;
  __syncthreads();
  if (amLast) {
    __threadfence();
    unsigned long long b = 0ull;
    for (int i = threadIdx.x; i < (int)gridDim.x; i += 256) {
      unsigned long long val = *((volatile unsigned long long*)(partials + i));
      if (val > b) b = val;
    }
    red[threadIdx.x] = b;
    __syncthreads();
    for (int s = 128; s; s >>= 1) {
      if (threadIdx.x < s) {
        if (red[threadIdx.x + s] > red[threadIdx.x]) red[threadIdx.x] = red[threadIdx.x + s];
      }
      __syncthreads();
    }
    if (threadIdx.x == 0)
      token_out[0] = (int)(0xFFFFFFFFu - (uint32_t)(red[0] & 0xFFFFFFFFull));
  }
}

// ---------------- row-wise log_softmax, in place ----------------
__global__ __launch_bounds__(256) void k_logsoftmax(float* __restrict__ C) {
  __shared__ float red[256];
  float* row = C + (size_t)blockIdx.x * VOC;
  float m = -INFINITY;
  for (int i = threadIdx.x; i < VOC; i += 256) m = fmaxf(m, row[i]);
  red[threadIdx.x] = m;
  __syncthreads();
  for (int s = 128; s; s >>= 1) {
    if (threadIdx.x < s) red[threadIdx.x] = fmaxf(red[threadIdx.x], red[threadIdx.x + s]);
    __syncthreads();
  }
  m = red[0];
  __syncthreads();
  float sum = 0.0f;
  for (int i = threadIdx.x; i < VOC; i += 256) sum += expf(row[i] - m);
  red[threadIdx.x] = sum;
  __syncthreads();
  for (int s = 128; s; s >>= 1) {
    if (threadIdx.x < s) red[threadIdx.x] += red[threadIdx.x + s];
    __syncthreads();
  }
  float lse = m + logf(red[0]);
  __syncthreads();
  for (int i = threadIdx.x; i < VOC; i += 256) row[i] = row[i] - lse;
}

// ---------------- launch ----------------
extern "C" void kernel_launch(void* const* d_in, const int* in_sizes, int n_in,
                              void* d_out, int out_size, void* d_ws, size_t ws_size,
                              hipStream_t stream) {
  (void)in_sizes; (void)n_in; (void)out_size;
  const int*   sent  = (const int*)  d_in[0];
  // d_in[1] = given_num, fixed at 64 by setup_inputs (reference freezes it at trace time).
  const float* emb   = (const float*)d_in[2];
  const float* Wih_l = (const float*)d_in[3];
  const float* Whh_l = (const float*)d_in[4];
  const float* bih_l = (const float*)d_in[5];
  const float* bhh_l = (const float*)d_in[6];
  const float* Wih_c = (const float*)d_in[7];
  const float* Whh_c = (const float*)d_in[8];
  const float* bih_c = (const float*)d_in[9];
  const float* bhh_c = (const float*)d_in[10];
  const float* Wtag  = (const float*)d_in[11];
  const float* btag  = (const float*)d_in[12];
  float* out = (float*)d_out;

  char* ws = (char*)d_ws;
  uint2*              keys     = (uint2*)(ws + 0);
  int*                tokens   = (int*)(ws + 1024);
  unsigned*           counters = (unsigned*)(ws + 2048);
  unsigned long long* partials = (unsigned long long*)(ws + 4096);      // up to 1024 entries
  float*              cbuf     = (float*)(ws + 12288);
  float*              h0       = (float*)(ws + 16384);
  float*              lstm_out = (float*)(ws + 20480);                  // 64x1024
  float*              hroll    = (float*)(ws + 20480 + 262144);         // 64x1024
  float*              X        = (float*)(ws + 20480 + 2 * 262144);     // 64x1024
  float*              gx       = (float*)(ws + 20480 + 3 * 262144);     // 64x4096
  const size_t WT16_OFF   = 2u * 1024u * 1024u;
  const size_t WT16_BYTES = (size_t)VOC * 1024u * 2u;
  unsigned short* Wt16 = (unsigned short*)(ws + WT16_OFF);
  bool use16 = (ws_size >= WT16_OFF + WT16_BYTES);

  k_init<<<1, 256, 0, stream>>>(keys, counters, cbuf, h0);
  if (use16)
    k_cvt_f16<<<2048, 256, 0, stream>>>(Wtag, Wt16, VOC * 1024);
  k_gather<<<GN, 256, 0, stream>>>(emb, sent, X);
  k_gemm64<<<G4 / 64, 256, 0, stream>>>(X, Wih_l, nullptr, gx, G4);
  for (int t = 0; t < GN; ++t) {
    const float* hp = t ? (lstm_out + (size_t)(t - 1) * HIDD) : h0;
    k_lstm_pre<<<HIDD, 256, 0, stream>>>(Whh_l, bih_l, bhh_l, gx, t, hp, cbuf,
                                         lstm_out + (size_t)t * HIDD);
  }
  if (use16)
    k_gemm64_f16b<<<VOC / 64, 256, 0, stream>>>(lstm_out, Wt16, btag, out, VOC);
  else
    k_gemm64<<<VOC / 64, 256, 0, stream>>>(lstm_out, Wtag, btag, out, VOC);
  k_sample_row<<<(VOC + 255) / 256, 256, 0, stream>>>(out + (size_t)(GN - 1) * VOC, keys, 0,
                                                      partials, counters + 64, tokens);
  for (int t = 0; t < NR; ++t) {
    const float* hp = t ? (hroll + (size_t)(t - 1) * HIDD) : (lstm_out + (size_t)(GN - 1) * HIDD);
    k_lstm_roll<<<HIDD, 256, 0, stream>>>(Wih_c, Whh_c, bih_c, bhh_c, emb, tokens, t, hp, cbuf,
                                          hroll + (size_t)t * HIDD);
    if (use16)
      k_logits_f16<<<VOC / 32, 256, 0, stream>>>(Wt16, btag, hroll + (size_t)t * HIDD,
                                                 out + (size_t)(GN + t) * VOC, keys, 1 + t,
                                                 partials, counters + t, tokens + t + 1);
    else
      k_logits<<<VOC / 64, 256, 0, stream>>>(Wtag, btag, hroll + (size_t)t * HIDD,
                                             out + (size_t)(GN + t) * VOC, keys, 1 + t,
                                             partials, counters + t, tokens + t + 1);
  }
  k_logsoftmax<<<SEQL, 256, 0, stream>>>(out);
}

// Round 2
// 4464.191 us; speedup vs baseline: 1.5311x; 1.5311x over previous
//
#include <hip/hip_runtime.h>
#include <hip/hip_fp16.h>
#include <cstdint>
#include <cstddef>

// Problem constants (reference freezes given_num=64 at trace time).
#define EMBD 1024
#define HIDD 1024
#define G4   4096
#define VOC  32000
#define SEQL 128
#define GN   64
#define NR   64

// JAX RNG mode: 1 = threefry_partitionable (modern JAX default), 0 = legacy stream.
#define JAX_PARTITIONABLE 1

// ---------------- threefry2x32 (JAX-compatible, 20 rounds) ----------------
__device__ __forceinline__ uint32_t rotl32(uint32_t v, int d) { return (v << d) | (v >> (32 - d)); }

__device__ inline void threefry2x32(uint32_t k0, uint32_t k1, uint32_t x0, uint32_t x1,
                                    uint32_t& o0, uint32_t& o1) {
  uint32_t ks2 = k0 ^ k1 ^ 0x1BD11BDAu;
#define TF_ROUND(r) { x0 += x1; x1 = rotl32(x1, r); x1 ^= x0; }
  x0 += k0;  x1 += k1;
  TF_ROUND(13) TF_ROUND(15) TF_ROUND(26) TF_ROUND(6)
  x0 += k1;  x1 += ks2 + 1u;
  TF_ROUND(17) TF_ROUND(29) TF_ROUND(16) TF_ROUND(24)
  x0 += ks2; x1 += k0 + 2u;
  TF_ROUND(13) TF_ROUND(15) TF_ROUND(26) TF_ROUND(6)
  x0 += k0;  x1 += k1 + 3u;
  TF_ROUND(17) TF_ROUND(29) TF_ROUND(16) TF_ROUND(24)
  x0 += k1;  x1 += ks2 + 4u;
  TF_ROUND(13) TF_ROUND(15) TF_ROUND(26) TF_ROUND(6)
  x0 += ks2; x1 += k0 + 5u;
#undef TF_ROUND
  o0 = x0; o1 = x1;
}

// 32-bit random draw for element idx of a length-VOC array under key (k0,k1).
__device__ inline uint32_t rng_bits(uint32_t k0, uint32_t k1, uint32_t idx) {
#if JAX_PARTITIONABLE
  uint32_t h0, h1; threefry2x32(k0, k1, 0u, idx, h0, h1);
  return h0 ^ h1;
#else
  uint32_t h0, h1;
  if (idx < (VOC / 2)) { threefry2x32(k0, k1, idx, idx + (VOC / 2), h0, h1); return h0; }
  else                 { threefry2x32(k0, k1, idx - (VOC / 2), idx, h0, h1); return h1; }
#endif
}

__device__ inline float gumbel_of(uint32_t k0, uint32_t k1, uint32_t idx) {
  uint32_t bits = rng_bits(k0, k1, idx);
  float u = __uint_as_float((bits >> 9) | 0x3f800000u) - 1.0f;   // [0,1)
  u = fmaxf(u, 1.17549435e-38f);                                  // jax uniform(minval=tiny)
  return -logf(-logf(u));
}

// argmax pack: bigger value wins; on exact tie, smaller index wins (jnp.argmax).
__device__ inline unsigned long long packCand(float v, int idx) {
  uint32_t u = __float_as_uint(v);
  u = (u & 0x80000000u) ? ~u : (u | 0x80000000u);
  return ((unsigned long long)u << 32) | (unsigned long long)(0xFFFFFFFFu - (uint32_t)idx);
}

__device__ inline float sigf(float x) { return 1.0f / (1.0f + expf(-x)); }

__device__ __forceinline__ float h2f(unsigned short u) {
  __half_raw hr; hr.x = u;
  return __half2float(__half(hr));
}

// ---------------- init: keys (split of key(123)), zero state ----------------
__global__ void k_init(uint2* keys, unsigned* counters, float* cbuf, float* h0) {
  int t = threadIdx.x;
#if JAX_PARTITIONABLE
  if (t < NR + 1) {
    uint32_t a, b; threefry2x32(0u, 123u, 0u, (uint32_t)t, a, b);
    keys[t] = make_uint2(a, b);
  }
#else
  __shared__ uint32_t buf[2 * (NR + 1)];
  if (t < NR + 1) {
    uint32_t a, b; threefry2x32(0u, 123u, (uint32_t)t, (uint32_t)(t + NR + 1), a, b);
    buf[t] = a; buf[t + NR + 1] = b;
  }
  __syncthreads();
  if (t < NR + 1) keys[t] = make_uint2(buf[2 * t], buf[2 * t + 1]);
#endif
  for (int i = t; i < 66; i += 256) counters[i] = 0u;
  for (int i = t; i < HIDD; i += 256) { cbuf[i] = 0.0f; h0[i] = 0.0f; }
}

// ---------------- Wtag fp32 -> fp16 conversion (once per launch) ----------------
__global__ __launch_bounds__(256) void k_cvt_f16(const float* __restrict__ src,
                                                 unsigned short* __restrict__ dst, int n) {
  int stride = gridDim.x * blockDim.x * 8;
  for (int i = (blockIdx.x * blockDim.x + threadIdx.x) * 8; i < n; i += stride) {
    float4 a = *(const float4*)(src + i);
    float4 b = *(const float4*)(src + i + 4);
    union { unsigned short u[8]; uint4 v; } p;
    __half t;
    t = __float2half(a.x); p.u[0] = __half_raw(t).x;
    t = __float2half(a.y); p.u[1] = __half_raw(t).x;
    t = __float2half(a.z); p.u[2] = __half_raw(t).x;
    t = __float2half(a.w); p.u[3] = __half_raw(t).x;
    t = __float2half(b.x); p.u[4] = __half_raw(t).x;
    t = __float2half(b.y); p.u[5] = __half_raw(t).x;
    t = __float2half(b.z); p.u[6] = __half_raw(t).x;
    t = __float2half(b.w); p.u[7] = __half_raw(t).x;
    *(uint4*)(dst + i) = p.v;
  }
}

// ---------------- gather prefix embeddings ----------------
__global__ void k_gather(const float* __restrict__ emb, const int* __restrict__ sent,
                         float* __restrict__ X) {
  int m = blockIdx.x;
  int row = sent[m];
  const float4* s = (const float4*)(emb + (size_t)row * EMBD);
  float4* d = (float4*)(X + (size_t)m * EMBD);
  d[threadIdx.x] = s[threadIdx.x];  // 256 float4 = 1024 floats
}

// ---------------- GEMM: C[64][N] = A[64][1024] @ B[N][1024]^T (+bias), fp32 B ----------------
__global__ __launch_bounds__(256) void k_gemm64(const float* __restrict__ A,
                                                const float* __restrict__ B,
                                                const float* __restrict__ bias,
                                                float* __restrict__ C, int ldc) {
  __shared__ float As[64][33];
  __shared__ float Bs[64][33];
  int n0 = blockIdx.x * 64;
  int tn = threadIdx.x & 15, tm = threadIdx.x >> 4;
  float acc[4][4] = {{0.f}};
  for (int k0 = 0; k0 < 1024; k0 += 32) {
    for (int f = threadIdx.x; f < 512; f += 256) {
      int r = f >> 3, c4 = (f & 7) << 2;
      float4 v = *(const float4*)(A + (size_t)r * 1024 + k0 + c4);
      As[r][c4 + 0] = v.x; As[r][c4 + 1] = v.y; As[r][c4 + 2] = v.z; As[r][c4 + 3] = v.w;
      float4 u = *(const float4*)(B + (size_t)(n0 + r) * 1024 + k0 + c4);
      Bs[r][c4 + 0] = u.x; Bs[r][c4 + 1] = u.y; Bs[r][c4 + 2] = u.z; Bs[r][c4 + 3] = u.w;
    }
    __syncthreads();
#pragma unroll
    for (int kk = 0; kk < 32; ++kk) {
      float a0 = As[tm * 4 + 0][kk], a1 = As[tm * 4 + 1][kk];
      float a2 = As[tm * 4 + 2][kk], a3 = As[tm * 4 + 3][kk];
      float b0 = Bs[tn * 4 + 0][kk], b1 = Bs[tn * 4 + 1][kk];
      float b2 = Bs[tn * 4 + 2][kk], b3 = Bs[tn * 4 + 3][kk];
      acc[0][0] += a0 * b0; acc[0][1] += a0 * b1; acc[0][2] += a0 * b2; acc[0][3] += a0 * b3;
      acc[1][0] += a1 * b0; acc[1][1] += a1 * b1; acc[1][2] += a1 * b2; acc[1][3] += a1 * b3;
      acc[2][0] += a2 * b0; acc[2][1] += a2 * b1; acc[2][2] += a2 * b2; acc[2][3] += a2 * b3;
      acc[3][0] += a3 * b0; acc[3][1] += a3 * b1; acc[3][2] += a3 * b2; acc[3][3] += a3 * b3;
    }
    __syncthreads();
  }
#pragma unroll
  for (int i = 0; i < 4; ++i)
#pragma unroll
    for (int j = 0; j < 4; ++j) {
      int m = tm * 4 + i, n = n0 + tn * 4 + j;
      float r = acc[i][j] + (bias ? bias[n] : 0.0f);
      C[(size_t)m * ldc + n] = r;
    }
}

// ---------------- GEMM variant: B in fp16 (for W_tag) ----------------
__global__ __launch_bounds__(256) void k_gemm64_f16b(const float* __restrict__ A,
                                                     const unsigned short* __restrict__ B16,
                                                     const float* __restrict__ bias,
                                                     float* __restrict__ C, int ldc) {
  __shared__ float As[64][33];
  __shared__ float Bs[64][33];
  int n0 = blockIdx.x * 64;
  int tn = threadIdx.x & 15, tm = threadIdx.x >> 4;
  float acc[4][4] = {{0.f}};
  for (int k0 = 0; k0 < 1024; k0 += 32) {
    for (int f = threadIdx.x; f < 512; f += 256) {
      int r = f >> 3, c4 = (f & 7) << 2;
      float4 v = *(const float4*)(A + (size_t)r * 1024 + k0 + c4);
      As[r][c4 + 0] = v.x; As[r][c4 + 1] = v.y; As[r][c4 + 2] = v.z; As[r][c4 + 3] = v.w;
    }
    {
      int f = threadIdx.x;
      int r = f >> 2, c8 = (f & 3) << 3;
      union { uint4 v; unsigned short u[8]; } p;
      p.v = *(const uint4*)(B16 + (size_t)(n0 + r) * 1024 + k0 + c8);
#pragma unroll
      for (int j = 0; j < 8; ++j) Bs[r][c8 + j] = h2f(p.u[j]);
    }
    __syncthreads();
#pragma unroll
    for (int kk = 0; kk < 32; ++kk) {
      float a0 = As[tm * 4 + 0][kk], a1 = As[tm * 4 + 1][kk];
      float a2 = As[tm * 4 + 2][kk], a3 = As[tm * 4 + 3][kk];
      float b0 = Bs[tn * 4 + 0][kk], b1 = Bs[tn * 4 + 1][kk];
      float b2 = Bs[tn * 4 + 2][kk], b3 = Bs[tn * 4 + 3][kk];
      acc[0][0] += a0 * b0; acc[0][1] += a0 * b1; acc[0][2] += a0 * b2; acc[0][3] += a0 * b3;
      acc[1][0] += a1 * b0; acc[1][1] += a1 * b1; acc[1][2] += a1 * b2; acc[1][3] += a1 * b3;
      acc[2][0] += a2 * b0; acc[2][1] += a2 * b1; acc[2][2] += a2 * b2; acc[2][3] += a2 * b3;
      acc[3][0] += a3 * b0; acc[3][1] += a3 * b1; acc[3][2] += a3 * b2; acc[3][3] += a3 * b3;
    }
    __syncthreads();
  }
#pragma unroll
  for (int i = 0; i < 4; ++i)
#pragma unroll
    for (int j = 0; j < 4; ++j) {
      int m = tm * 4 + i, n = n0 + tn * 4 + j;
      float r = acc[i][j] + (bias ? bias[n] : 0.0f);
      C[(size_t)m * ldc + n] = r;
    }
}

// ---------------- prefix LSTM step (x-part precomputed in gx) ----------------
__global__ __launch_bounds__(256) void k_lstm_pre(const float* __restrict__ Whh,
                                                  const float* __restrict__ bih,
                                                  const float* __restrict__ bhh,
                                                  const float* __restrict__ gx, int t,
                                                  const float* __restrict__ hprev,
                                                  float* __restrict__ cbuf,
                                                  float* __restrict__ hout) {
  __shared__ float gs[4];
  int wave = threadIdx.x >> 6, lane = threadIdx.x & 63;
  int j = blockIdx.x;
  int r = j + (wave << 10);
  const float4* h4 = (const float4*)hprev;
  const float4* w4 = (const float4*)(Whh + (size_t)r * 1024);
  float a = 0.0f;
#pragma unroll
  for (int q = 0; q < 4; ++q) {
    float4 w = w4[lane + (q << 6)];
    float4 h = h4[lane + (q << 6)];
    a += w.x * h.x + w.y * h.y + w.z * h.z + w.w * h.w;
  }
#pragma unroll
  for (int off = 32; off; off >>= 1) a += __shfl_xor(a, off, 64);
  if (lane == 0) gs[wave] = a + gx[(size_t)t * G4 + r] + bih[r] + bhh[r];
  __syncthreads();
  if (threadIdx.x == 0) {
    float gi = gs[0], gf = gs[1], gg = gs[2], go = gs[3];
    float cn = sigf(gf) * cbuf[j] + sigf(gi) * tanhf(gg);
    cbuf[j] = cn;
    hout[j] = sigf(go) * tanhf(cn);
  }
}

// ---------------- rollout LSTM step (x = emb[tokens[t]]) ----------------
__global__ __launch_bounds__(256) void k_lstm_roll(const float* __restrict__ Wih,
                                                   const float* __restrict__ Whh,
                                                   const float* __restrict__ bih,
                                                   const float* __restrict__ bhh,
                                                   const float* __restrict__ emb,
                                                   const int* __restrict__ tok, int t,
                                                   const float* __restrict__ hprev,
                                                   float* __restrict__ cbuf,
                                                   float* __restrict__ hout) {
  __shared__ float gs[4];
  int wave = threadIdx.x >> 6, lane = threadIdx.x & 63;
  int j = blockIdx.x;
  int r = j + (wave << 10);
  int row = tok[t];
  const float4* x4 = (const float4*)(emb + (size_t)row * EMBD);
  const float4* h4 = (const float4*)hprev;
  const float4* wi = (const float4*)(Wih + (size_t)r * 1024);
  const float4* wh = (const float4*)(Whh + (size_t)r * 1024);
  float a = 0.0f;
#pragma unroll
  for (int q = 0; q < 4; ++q) {
    float4 w = wi[lane + (q << 6)];
    float4 x = x4[lane + (q << 6)];
    a += w.x * x.x + w.y * x.y + w.z * x.z + w.w * x.w;
    w = wh[lane + (q << 6)];
    float4 h = h4[lane + (q << 6)];
    a += w.x * h.x + w.y * h.y + w.z * h.z + w.w * h.w;
  }
#pragma unroll
  for (int off = 32; off; off >>= 1) a += __shfl_xor(a, off, 64);
  if (lane == 0) gs[wave] = a + bih[r] + bhh[r];
  __syncthreads();
  if (threadIdx.x == 0) {
    float gi = gs[0], gf = gs[1], gg = gs[2], go = gs[3];
    float cn = sigf(gf) * cbuf[j] + sigf(gi) * tanhf(gg);
    cbuf[j] = cn;
    hout[j] = sigf(go) * tanhf(cn);
  }
}

// ---------------- logits matvec + gumbel + argmax, fp32 Wtag (fallback) ----------------
__global__ __launch_bounds__(256) void k_logits(const float* __restrict__ Wtag,
                                                const float* __restrict__ btag,
                                                const float* __restrict__ h,
                                                float* __restrict__ outrow,
                                                const uint2* __restrict__ keys, int key_idx,
                                                unsigned long long* __restrict__ partials,
                                                unsigned* __restrict__ counter,
                                                int* __restrict__ token_out) {
  __shared__ float sums[64];
  __shared__ unsigned long long red[256];
  __shared__ int amLast;
  int wave = threadIdx.x >> 6, lane = threadIdx.x & 63;
  int r0 = blockIdx.x * 64;
  const float4* h4 = (const float4*)h;
  float4 hv[4];
#pragma unroll
  for (int q = 0; q < 4; ++q) hv[q] = h4[lane + (q << 6)];
  for (int rr = 0; rr < 16; ++rr) {
    int lr = wave * 16 + rr;
    int r = r0 + lr;
    const float4* w4 = (const float4*)(Wtag + (size_t)r * 1024);
    float a = 0.0f;
#pragma unroll
    for (int q = 0; q < 4; ++q) {
      float4 w = w4[lane + (q << 6)];
      a += w.x * hv[q].x + w.y * hv[q].y + w.z * hv[q].z + w.w * hv[q].w;
    }
#pragma unroll
    for (int off = 32; off; off >>= 1) a += __shfl_xor(a, off, 64);
    if (lane == 0) sums[lr] = a;
  }
  __syncthreads();
  unsigned long long best = 0ull;
  if (threadIdx.x < 64) {
    int r = r0 + threadIdx.x;
    float L = sums[threadIdx.x] + btag[r];
    outrow[r] = L;
    uint2 K = keys[key_idx];
    float y = L + gumbel_of(K.x, K.y, (uint32_t)r);
    best = packCand(y, r);
#pragma unroll
    for (int off = 32; off; off >>= 1) {
      unsigned long long o = __shfl_xor(best, off, 64);
      if (o > best) best = o;
    }
    if (threadIdx.x == 0) partials[blockIdx.x] = best;
  }
  __threadfence();
  __syncthreads();
  if (threadIdx.x == 0) amLast = (atomicAdd(counter, 1u) == gridDim.x - 1) ? 1 : 0;
  __syncthreads();
  if (amLast) {
    __threadfence();
    unsigned long long b = 0ull;
    for (int i = threadIdx.x; i < (int)gridDim.x; i += 256) {
      unsigned long long v = *((volatile unsigned long long*)(partials + i));
      if (v > b) b = v;
    }
    red[threadIdx.x] = b;
    __syncthreads();
    for (int s = 128; s; s >>= 1) {
      if (threadIdx.x < s) {
        if (red[threadIdx.x + s] > red[threadIdx.x]) red[threadIdx.x] = red[threadIdx.x + s];
      }
      __syncthreads();
    }
    if (threadIdx.x == 0)
      token_out[0] = (int)(0xFFFFFFFFu - (uint32_t)(red[0] & 0xFFFFFFFFull));
  }
}

// ---------------- logits matvec + gumbel + argmax, fp16 Wtag ----------------
// EXACT round-0 outer structure (grid VOC/64, 64 rows/block, 16 rows/wave,
// same tail/reduction). Only the weight loads change: 2x uint4 (fp16) per
// row per lane instead of 4x float4 -> 32 independent loads/lane, half bytes.
__global__ __launch_bounds__(256) void k_logits_f16(const unsigned short* __restrict__ Wt16,
                                                    const float* __restrict__ btag,
                                                    const float* __restrict__ h,
                                                    float* __restrict__ outrow,
                                                    const uint2* __restrict__ keys, int key_idx,
                                                    unsigned long long* __restrict__ partials,
                                                    unsigned* __restrict__ counter,
                                                    int* __restrict__ token_out) {
  __shared__ float sums[64];
  __shared__ unsigned long long red[256];
  __shared__ int amLast;
  int wave = threadIdx.x >> 6, lane = threadIdx.x & 63;
  int r0 = blockIdx.x * 64;
  const float4* h4 = (const float4*)h;
  // lane covers floats [q*512 + lane*8, +8) for q=0,1 -> 4 float4 of h
  float4 hq[4];
#pragma unroll
  for (int q = 0; q < 2; ++q) {
    hq[2 * q]     = h4[q * 128 + lane * 2];
    hq[2 * q + 1] = h4[q * 128 + lane * 2 + 1];
  }
  for (int rr = 0; rr < 16; ++rr) {
    int lr = wave * 16 + rr;
    int r = r0 + lr;
    const unsigned short* wrow = Wt16 + (size_t)r * 1024;
    float a = 0.0f;
#pragma unroll
    for (int q = 0; q < 2; ++q) {
      union { uint4 v; unsigned short u[8]; } p;
      p.v = *(const uint4*)(wrow + q * 512 + lane * 8);
      float4 hA = hq[2 * q], hB = hq[2 * q + 1];
      a += h2f(p.u[0]) * hA.x; a += h2f(p.u[1]) * hA.y;
      a += h2f(p.u[2]) * hA.z; a += h2f(p.u[3]) * hA.w;
      a += h2f(p.u[4]) * hB.x; a += h2f(p.u[5]) * hB.y;
      a += h2f(p.u[6]) * hB.z; a += h2f(p.u[7]) * hB.w;
    }
#pragma unroll
    for (int off = 32; off; off >>= 1) a += __shfl_xor(a, off, 64);
    if (lane == 0) sums[lr] = a;
  }
  __syncthreads();
  unsigned long long best = 0ull;
  if (threadIdx.x < 64) {
    int r = r0 + threadIdx.x;
    float L = sums[threadIdx.x] + btag[r];
    outrow[r] = L;
    uint2 K = keys[key_idx];
    float y = L + gumbel_of(K.x, K.y, (uint32_t)r);
    best = packCand(y, r);
#pragma unroll
    for (int off = 32; off; off >>= 1) {
      unsigned long long o = __shfl_xor(best, off, 64);
      if (o > best) best = o;
    }
    if (threadIdx.x == 0) partials[blockIdx.x] = best;
  }
  __threadfence();
  __syncthreads();
  if (threadIdx.x == 0) amLast = (atomicAdd(counter, 1u) == gridDim.x - 1) ? 1 : 0;
  __syncthreads();
  if (amLast) {
    __threadfence();
    unsigned long long b = 0ull;
    for (int i = threadIdx.x; i < (int)gridDim.x; i += 256) {
      unsigned long long v = *((volatile unsigned long long*)(partials + i));
      if (v > b) b = v;
    }
    red[threadIdx.x] = b;
    __syncthreads();
    for (int s = 128; s; s >>= 1) {
      if (threadIdx.x < s) {
        if (red[threadIdx.x + s] > red[threadIdx.x]) red[threadIdx.x] = red[threadIdx.x + s];
      }
      __syncthreads();
    }
    if (threadIdx.x == 0)
      token_out[0] = (int)(0xFFFFFFFFu - (uint32_t)(red[0] & 0xFFFFFFFFull));
  }
}

// ---------------- sample from an existing logits row (initial token) ----------------
__global__ __launch_bounds__(256) void k_sample_row(const float* __restrict__ row,
                                                    const uint2* __restrict__ keys, int key_idx,
                                                    unsigned long long* __restrict__ partials,
                                                    unsigned* __restrict__ counter,
                                                    int* __restrict__ token_out) {
  __shared__ unsigned long long red[256];
  __shared__ int amLast;
  int v = blockIdx.x * 256 + threadIdx.x;
  unsigned long long best = 0ull;
  if (v < VOC) {
    uint2 K = keys[key_idx];
    float y = row[v] + gumbel_of(K.x, K.y, (uint32_t)v);
    best = packCand(y, v);
  }
  red[threadIdx.x] = best;
  __syncthreads();
  for (int s = 128; s; s >>= 1) {
    if (threadIdx.x < s) {
      if (red[threadIdx.x + s] > red[threadIdx.x]) red[threadIdx.x] = red[threadIdx.x + s];
    }
    __syncthreads();
  }
  if (threadIdx.x == 0) partials[blockIdx.x] = red[0];
  __threadfence();
  __syncthreads();
  if (threadIdx.x == 0) amLast = (atomicAdd(counter, 1u) == gridDim.x - 1) ? 1 : 0;
  __syncthreads();
  if (amLast) {
    __threadfence();
    unsigned long long b = 0ull;
    for (int i = threadIdx.x; i < (int)gridDim.x; i += 256) {
      unsigned long long val = *((volatile unsigned long long*)(partials + i));
      if (val > b) b = val;
    }
    red[threadIdx.x] = b;
    __syncthreads();
    for (int s = 128; s; s >>= 1) {
      if (threadIdx.x < s) {
        if (red[threadIdx.x + s] > red[threadIdx.x]) red[threadIdx.x] = red[threadIdx.x + s];
      }
      __syncthreads();
    }
    if (threadIdx.x == 0)
      token_out[0] = (int)(0xFFFFFFFFu - (uint32_t)(red[0] & 0xFFFFFFFFull));
  }
}

// ---------------- row-wise log_softmax, in place ----------------
__global__ __launch_bounds__(256) void k_logsoftmax(float* __restrict__ C) {
  __shared__ float red[256];
  float* row = C + (size_t)blockIdx.x * VOC;
  float m = -INFINITY;
  for (int i = threadIdx.x; i < VOC; i += 256) m = fmaxf(m, row[i]);
  red[threadIdx.x] = m;
  __syncthreads();
  for (int s = 128; s; s >>= 1) {
    if (threadIdx.x < s) red[threadIdx.x] = fmaxf(red[threadIdx.x], red[threadIdx.x + s]);
    __syncthreads();
  }
  m = red[0];
  __syncthreads();
  float sum = 0.0f;
  for (int i = threadIdx.x; i < VOC; i += 256) sum += expf(row[i] - m);
  red[threadIdx.x] = sum;
  __syncthreads();
  for (int s = 128; s; s >>= 1) {
    if (threadIdx.x < s) red[threadIdx.x] += red[threadIdx.x + s];
    __syncthreads();
  }
  float lse = m + logf(red[0]);
  __syncthreads();
  for (int i = threadIdx.x; i < VOC; i += 256) row[i] = row[i] - lse;
}

// ---------------- launch ----------------
extern "C" void kernel_launch(void* const* d_in, const int* in_sizes, int n_in,
                              void* d_out, int out_size, void* d_ws, size_t ws_size,
                              hipStream_t stream) {
  (void)in_sizes; (void)n_in; (void)out_size;
  const int*   sent  = (const int*)  d_in[0];
  // d_in[1] = given_num, fixed at 64 by setup_inputs (reference freezes it at trace time).
  const float* emb   = (const float*)d_in[2];
  const float* Wih_l = (const float*)d_in[3];
  const float* Whh_l = (const float*)d_in[4];
  const float* bih_l = (const float*)d_in[5];
  const float* bhh_l = (const float*)d_in[6];
  const float* Wih_c = (const float*)d_in[7];
  const float* Whh_c = (const float*)d_in[8];
  const float* bih_c = (const float*)d_in[9];
  const float* bhh_c = (const float*)d_in[10];
  const float* Wtag  = (const float*)d_in[11];
  const float* btag  = (const float*)d_in[12];
  float* out = (float*)d_out;

  char* ws = (char*)d_ws;
  uint2*              keys     = (uint2*)(ws + 0);
  int*                tokens   = (int*)(ws + 1024);
  unsigned*           counters = (unsigned*)(ws + 2048);
  unsigned long long* partials = (unsigned long long*)(ws + 4096);      // up to 1024 entries
  float*              cbuf     = (float*)(ws + 12288);
  float*              h0       = (float*)(ws + 16384);
  float*              lstm_out = (float*)(ws + 20480);                  // 64x1024
  float*              hroll    = (float*)(ws + 20480 + 262144);         // 64x1024
  float*              X        = (float*)(ws + 20480 + 2 * 262144);     // 64x1024
  float*              gx       = (float*)(ws + 20480 + 3 * 262144);     // 64x4096
  const size_t WT16_OFF   = 2u * 1024u * 1024u;
  const size_t WT16_BYTES = (size_t)VOC * 1024u * 2u;
  unsigned short* Wt16 = (unsigned short*)(ws + WT16_OFF);
  bool use16 = (ws_size >= WT16_OFF + WT16_BYTES);

  k_init<<<1, 256, 0, stream>>>(keys, counters, cbuf, h0);
  if (use16)
    k_cvt_f16<<<2048, 256, 0, stream>>>(Wtag, Wt16, VOC * 1024);
  k_gather<<<GN, 256, 0, stream>>>(emb, sent, X);
  k_gemm64<<<G4 / 64, 256, 0, stream>>>(X, Wih_l, nullptr, gx, G4);
  for (int t = 0; t < GN; ++t) {
    const float* hp = t ? (lstm_out + (size_t)(t - 1) * HIDD) : h0;
    k_lstm_pre<<<HIDD, 256, 0, stream>>>(Whh_l, bih_l, bhh_l, gx, t, hp, cbuf,
                                         lstm_out + (size_t)t * HIDD);
  }
  if (use16)
    k_gemm64_f16b<<<VOC / 64, 256, 0, stream>>>(lstm_out, Wt16, btag, out, VOC);
  else
    k_gemm64<<<VOC / 64, 256, 0, stream>>>(lstm_out, Wtag, btag, out, VOC);
  k_sample_row<<<(VOC + 255) / 256, 256, 0, stream>>>(out + (size_t)(GN - 1) * VOC, keys, 0,
                                                      partials, counters + 64, tokens);
  for (int t = 0; t < NR; ++t) {
    const float* hp = t ? (hroll + (size_t)(t - 1) * HIDD) : (lstm_out + (size_t)(GN - 1) * HIDD);
    k_lstm_roll<<<HIDD, 256, 0, stream>>>(Wih_c, Whh_c, bih_c, bhh_c, emb, tokens, t, hp, cbuf,
                                          hroll + (size_t)t * HIDD);
    if (use16)
      k_logits_f16<<<VOC / 64, 256, 0, stream>>>(Wt16, btag, hroll + (size_t)t * HIDD,
                                                 out + (size_t)(GN + t) * VOC, keys, 1 + t,
                                                 partials, counters + t, tokens + t + 1);
    else
      k_logits<<<VOC / 64, 256, 0, stream>>>(Wtag, btag, hroll + (size_t)t * HIDD,
                                             out + (size_t)(GN + t) * VOC, keys, 1 + t,
                                             partials, counters + t, tokens + t + 1);
  }
  k_logsoftmax<<<SEQL, 256, 0, stream>>>(out);
}